// Round 2
// baseline (603.008 us; speedup 1.0000x reference)
//
#include <hip/hip_runtime.h>
#include <hip/hip_bf16.h>
#include <math.h>

#define B_ 4
#define N_ 1024
#define C_ 768
#define H_ 12
#define D_ 64
#define TOPK_ 32
#define EPS_ 1e-9f

// ---------------------------------------------------------------------------
// Generic NN GEMM: C[M,Nc] = A[M,K] @ B[K,Nc] + bias[Nc]
// 64x64 block tile, 16 K-chunk, 256 threads, 4x4 micro-tile per thread.
// ---------------------------------------------------------------------------
__global__ __launch_bounds__(256) void gemm_nn_bias(
    const float* __restrict__ A, const float* __restrict__ Bm,
    const float* __restrict__ bias, float* __restrict__ Cm,
    int M, int Ncols, int Kdim, int lda, int ldb, int ldc)
{
    __shared__ float As[16][68];   // transposed: As[kk][row]
    __shared__ float Bs[16][68];   // natural:    Bs[kk][col]
    const int t  = threadIdx.x;
    const int tx = t & 15, ty = t >> 4;
    const int m0 = blockIdx.y * 64, n0 = blockIdx.x * 64;
    const int arow = t >> 2, akk = (t & 3) * 4;
    const int bkk  = t >> 4, bcol = (t & 15) * 4;

    float acc[4][4] = {{0.f, 0.f, 0.f, 0.f}, {0.f, 0.f, 0.f, 0.f},
                       {0.f, 0.f, 0.f, 0.f}, {0.f, 0.f, 0.f, 0.f}};

    for (int k0 = 0; k0 < Kdim; k0 += 16) {
        float4 av = *(const float4*)&A[(size_t)(m0 + arow) * lda + k0 + akk];
        float4 bv = *(const float4*)&Bm[(size_t)(k0 + bkk) * ldb + n0 + bcol];
        __syncthreads();
        As[akk + 0][arow] = av.x;
        As[akk + 1][arow] = av.y;
        As[akk + 2][arow] = av.z;
        As[akk + 3][arow] = av.w;
        *(float4*)&Bs[bkk][bcol] = bv;
        __syncthreads();
        #pragma unroll
        for (int kk = 0; kk < 16; ++kk) {
            float4 a  = *(const float4*)&As[kk][ty * 4];
            float4 b4 = *(const float4*)&Bs[kk][tx * 4];
            float ar[4] = {a.x, a.y, a.z, a.w};
            float br[4] = {b4.x, b4.y, b4.z, b4.w};
            #pragma unroll
            for (int i = 0; i < 4; ++i)
                #pragma unroll
                for (int j = 0; j < 4; ++j)
                    acc[i][j] += ar[i] * br[j];
        }
    }
    #pragma unroll
    for (int i = 0; i < 4; ++i) {
        float4 o;
        o.x = acc[i][0] + bias[n0 + tx * 4 + 0];
        o.y = acc[i][1] + bias[n0 + tx * 4 + 1];
        o.z = acc[i][2] + bias[n0 + tx * 4 + 2];
        o.w = acc[i][3] + bias[n0 + tx * 4 + 3];
        *(float4*)&Cm[(size_t)(m0 + ty * 4 + i) * ldc + n0 + tx * 4] = o;
    }
}

// ---------------------------------------------------------------------------
// z[b,n,m] = (scale/H) * Qc[b,n,:].Kc[b,m,:] + gumbel(u[b,n,m])
// Qc = qkv row offset 0, Kc = qkv row offset 768 (full 768-dim vectors).
// ---------------------------------------------------------------------------
__global__ __launch_bounds__(256) void zscore_kernel(
    const float* __restrict__ qkv, const float* __restrict__ u,
    float* __restrict__ z)
{
    __shared__ float As[16][68];   // As[kk][n]
    __shared__ float Bs[16][68];   // Bs[kk][m]
    const int t  = threadIdx.x;
    const int tx = t & 15, ty = t >> 4;
    const int b  = blockIdx.z;
    const int n0 = blockIdx.y * 64, m0 = blockIdx.x * 64;
    const int lrow = t >> 2, lkk = (t & 3) * 4;
    const float* qbase = qkv + (size_t)b * N_ * 2304;

    float acc[4][4] = {{0.f, 0.f, 0.f, 0.f}, {0.f, 0.f, 0.f, 0.f},
                       {0.f, 0.f, 0.f, 0.f}, {0.f, 0.f, 0.f, 0.f}};

    for (int k0 = 0; k0 < C_; k0 += 16) {
        float4 av = *(const float4*)&qbase[(size_t)(n0 + lrow) * 2304 + k0 + lkk];
        float4 bv = *(const float4*)&qbase[(size_t)(m0 + lrow) * 2304 + 768 + k0 + lkk];
        __syncthreads();
        As[lkk + 0][lrow] = av.x;
        As[lkk + 1][lrow] = av.y;
        As[lkk + 2][lrow] = av.z;
        As[lkk + 3][lrow] = av.w;
        Bs[lkk + 0][lrow] = bv.x;
        Bs[lkk + 1][lrow] = bv.y;
        Bs[lkk + 2][lrow] = bv.z;
        Bs[lkk + 3][lrow] = bv.w;
        __syncthreads();
        #pragma unroll
        for (int kk = 0; kk < 16; ++kk) {
            float4 a  = *(const float4*)&As[kk][ty * 4];
            float4 b4 = *(const float4*)&Bs[kk][tx * 4];
            float ar[4] = {a.x, a.y, a.z, a.w};
            float br[4] = {b4.x, b4.y, b4.z, b4.w};
            #pragma unroll
            for (int i = 0; i < 4; ++i)
                #pragma unroll
                for (int j = 0; j < 4; ++j)
                    acc[i][j] += ar[i] * br[j];
        }
    }
    const float sc = 0.125f / 12.0f;   // scale / H
    #pragma unroll
    for (int i = 0; i < 4; ++i) {
        const int n = n0 + ty * 4 + i;
        float4 o;
        float vals[4];
        #pragma unroll
        for (int j = 0; j < 4; ++j) {
            const int m = m0 + tx * 4 + j;
            float uv = u[((size_t)b * N_ + n) * N_ + m];
            float g  = -logf(-logf(uv + EPS_) + EPS_);
            vals[j]  = acc[i][j] * sc + g;
        }
        o.x = vals[0]; o.y = vals[1]; o.z = vals[2]; o.w = vals[3];
        *(float4*)&z[((size_t)b * N_ + n) * N_ + m0 + tx * 4] = o;
    }
}

// ---------------------------------------------------------------------------
// Per row: find 32nd-largest of z[row, 0..1023] exactly, emit bitmask
// mask[row][m] = (z >= thresh). One wave (64 lanes) per row, 16 elems/lane.
// ---------------------------------------------------------------------------
__global__ __launch_bounds__(64) void topk_mask_kernel(
    const float* __restrict__ z, unsigned long long* __restrict__ mask)
{
    const int row  = blockIdx.x;
    const int lane = threadIdx.x;
    const float* zr = z + (size_t)row * N_;
    float zv[16], wk[16];
    #pragma unroll
    for (int j = 0; j < 16; ++j) { zv[j] = zr[lane + 64 * j]; wk[j] = zv[j]; }

    float thresh = -INFINITY;
    for (int it = 0; it < TOPK_; ++it) {
        float lm = wk[0]; int li = 0;
        #pragma unroll
        for (int j = 1; j < 16; ++j)
            if (wk[j] > lm) { lm = wk[j]; li = j; }
        float gm = lm;
        gm = fmaxf(gm, __shfl_xor(gm, 1));
        gm = fmaxf(gm, __shfl_xor(gm, 2));
        gm = fmaxf(gm, __shfl_xor(gm, 4));
        gm = fmaxf(gm, __shfl_xor(gm, 8));
        gm = fmaxf(gm, __shfl_xor(gm, 16));
        gm = fmaxf(gm, __shfl_xor(gm, 32));
        unsigned long long has = __ballot(lm == gm);
        int first = __ffsll((unsigned long long)has) - 1;
        if (lane == first) wk[li] = -INFINITY;
        thresh = gm;
    }
    #pragma unroll
    for (int j = 0; j < 16; ++j) {
        unsigned long long w = __ballot(zv[j] >= thresh);
        if (lane == j) mask[(size_t)row * 16 + j] = w;
    }
}

// ---------------------------------------------------------------------------
// Fused masked flash attention per (b, h, 64-row tile):
//   attn = softmax_row(q.k^T * 0.125) * mask ; out1 = (attn @ v) * hs_mean
// Denominator over ALL columns; mask zeroes numerator contributions only.
// Tiles are 64 rows x 64 d = 4096 floats: each of 256 threads stages FOUR
// float4 (row lr = t>>2, d-base dq = (t&3)*16).
// ---------------------------------------------------------------------------
__global__ __launch_bounds__(256) void flash_masked_kernel(
    const float* __restrict__ qkv, const unsigned long long* __restrict__ maskp,
    const float* __restrict__ head_scores, float* __restrict__ out1)
{
    __shared__ float Qs[64][68];    // Qs[d][r]  (transposed)
    __shared__ float KVs[64][68];   // K phase: [d][c] transposed; V phase: [c][d]
    __shared__ float P[64][68];     // masked probs [r][c]

    const int t  = threadIdx.x;
    const int tx = t & 15, ty = t >> 4;
    const int n0 = blockIdx.x * 64;
    const int h  = blockIdx.y;
    const int b  = blockIdx.z;
    const int lr = t >> 2;           // staged row/col 0..63
    const int dq = (t & 3) * 16;     // staged d-base: 0,16,32,48

    float hsum = 0.f;
    #pragma unroll
    for (int i = 0; i < H_; ++i) hsum += head_scores[i];
    const float hs_mean = hsum * (1.0f / 12.0f);

    // Load Q tile (transposed): d = dq..dq+15 for row lr
    #pragma unroll
    for (int qq = 0; qq < 4; ++qq) {
        float4 qv = *(const float4*)
            &qkv[(size_t)(b * N_ + n0 + lr) * 2304 + h * 64 + dq + qq * 4];
        Qs[dq + qq * 4 + 0][lr] = qv.x;
        Qs[dq + qq * 4 + 1][lr] = qv.y;
        Qs[dq + qq * 4 + 2][lr] = qv.z;
        Qs[dq + qq * 4 + 3][lr] = qv.w;
    }

    float O[4][4] = {{0.f, 0.f, 0.f, 0.f}, {0.f, 0.f, 0.f, 0.f},
                     {0.f, 0.f, 0.f, 0.f}, {0.f, 0.f, 0.f, 0.f}};
    float mrun[4], lsum[4];
    #pragma unroll
    for (int i = 0; i < 4; ++i) { mrun[i] = -INFINITY; lsum[i] = 0.f; }

    for (int m0 = 0; m0 < N_; m0 += 64) {
        // issue K and V loads early (4 float4 each)
        float4 kv[4], vv[4];
        #pragma unroll
        for (int qq = 0; qq < 4; ++qq) {
            kv[qq] = *(const float4*)
                &qkv[(size_t)(b * N_ + m0 + lr) * 2304 + 768  + h * 64 + dq + qq * 4];
            vv[qq] = *(const float4*)
                &qkv[(size_t)(b * N_ + m0 + lr) * 2304 + 1536 + h * 64 + dq + qq * 4];
        }

        __syncthreads();                 // prev PV done with KVs / P
        #pragma unroll
        for (int qq = 0; qq < 4; ++qq) { // K transposed [d][c]
            KVs[dq + qq * 4 + 0][lr] = kv[qq].x;
            KVs[dq + qq * 4 + 1][lr] = kv[qq].y;
            KVs[dq + qq * 4 + 2][lr] = kv[qq].z;
            KVs[dq + qq * 4 + 3][lr] = kv[qq].w;
        }
        __syncthreads();

        // scores S[r][c] = 0.125 * sum_d Q[r][d]*K[c][d]
        float s[4][4] = {{0.f, 0.f, 0.f, 0.f}, {0.f, 0.f, 0.f, 0.f},
                         {0.f, 0.f, 0.f, 0.f}, {0.f, 0.f, 0.f, 0.f}};
        #pragma unroll 8
        for (int d = 0; d < 64; ++d) {
            float4 a  = *(const float4*)&Qs[d][ty * 4];
            float4 b4 = *(const float4*)&KVs[d][tx * 4];
            float ar[4] = {a.x, a.y, a.z, a.w};
            float br[4] = {b4.x, b4.y, b4.z, b4.w};
            #pragma unroll
            for (int i = 0; i < 4; ++i)
                #pragma unroll
                for (int j = 0; j < 4; ++j)
                    s[i][j] += ar[i] * br[j];
        }

        // online softmax update (per row), masked P write
        #pragma unroll
        for (int i = 0; i < 4; ++i) {
            float tmax = fmaxf(fmaxf(s[i][0], s[i][1]), fmaxf(s[i][2], s[i][3]));
            tmax *= 0.125f;              // scale>0: max commutes with scaling
            tmax = fmaxf(tmax, __shfl_xor(tmax, 1));
            tmax = fmaxf(tmax, __shfl_xor(tmax, 2));
            tmax = fmaxf(tmax, __shfl_xor(tmax, 4));
            tmax = fmaxf(tmax, __shfl_xor(tmax, 8));
            float mnew  = fmaxf(mrun[i], tmax);
            float alpha = expf(mrun[i] - mnew);
            float p[4], tsum = 0.f;
            #pragma unroll
            for (int j = 0; j < 4; ++j) {
                p[j] = expf(s[i][j] * 0.125f - mnew);
                tsum += p[j];
            }
            tsum += __shfl_xor(tsum, 1);
            tsum += __shfl_xor(tsum, 2);
            tsum += __shfl_xor(tsum, 4);
            tsum += __shfl_xor(tsum, 8);
            lsum[i] = lsum[i] * alpha + tsum;
            mrun[i] = mnew;
            O[i][0] *= alpha; O[i][1] *= alpha; O[i][2] *= alpha; O[i][3] *= alpha;
            unsigned long long w =
                maskp[(size_t)(b * N_ + n0 + ty * 4 + i) * 16 + (m0 >> 6)];
            #pragma unroll
            for (int j = 0; j < 4; ++j)
                P[ty * 4 + i][tx * 4 + j] = ((w >> (tx * 4 + j)) & 1ull) ? p[j] : 0.f;
        }
        __syncthreads();                 // scores done reading KVs(K); P written
        // store V natural [c][d]: row lr, d = dq..dq+15
        #pragma unroll
        for (int qq = 0; qq < 4; ++qq)
            *(float4*)&KVs[lr][dq + qq * 4] = vv[qq];
        __syncthreads();

        // O[r][d] += sum_c P[r][c] * V[c][d]
        #pragma unroll 8
        for (int cc = 0; cc < 64; ++cc) {
            float4 v4 = *(const float4*)&KVs[cc][tx * 4];
            float vr[4] = {v4.x, v4.y, v4.z, v4.w};
            #pragma unroll
            for (int i = 0; i < 4; ++i) {
                float pv = P[ty * 4 + i][cc];
                #pragma unroll
                for (int j = 0; j < 4; ++j)
                    O[i][j] += pv * vr[j];
            }
        }
    }

    // epilogue: divide by full-row softmax denominator, * hs_mean
    #pragma unroll
    for (int i = 0; i < 4; ++i) {
        float inv = hs_mean / lsum[i];
        float4 o;
        o.x = O[i][0] * inv;
        o.y = O[i][1] * inv;
        o.z = O[i][2] * inv;
        o.w = O[i][3] * inv;
        *(float4*)&out1[(size_t)(b * N_ + n0 + ty * 4 + i) * C_ + h * 64 + tx * 4] = o;
    }
}

// ---------------------------------------------------------------------------
extern "C" void kernel_launch(void* const* d_in, const int* in_sizes, int n_in,
                              void* d_out, int out_size, void* d_ws, size_t ws_size,
                              hipStream_t stream)
{
    (void)in_sizes; (void)n_in; (void)out_size; (void)ws_size;
    const float* x           = (const float*)d_in[0];
    const float* u           = (const float*)d_in[1];
    const float* qkv_w       = (const float*)d_in[2];
    const float* qkv_b       = (const float*)d_in[3];
    const float* proj_w      = (const float*)d_in[4];
    const float* proj_b      = (const float*)d_in[5];
    const float* head_scores = (const float*)d_in[6];
    float* out = (float*)d_out;

    char* ws = (char*)d_ws;
    float* ws_qkv = (float*)ws;                                   // 37,748,736 B
    float* ws_z   = (float*)(ws + 37748736);                      // 16,777,216 B
    unsigned long long* ws_mask =
        (unsigned long long*)(ws + 37748736 + 16777216);          //    524,288 B
    float* ws_out1 = ws_z;  // z dead after topk; reuse for attention output

    dim3 blk(256);

    // 1) qkv = x @ qkv_w + qkv_b   (4096 x 2304 x 768)
    gemm_nn_bias<<<dim3(2304 / 64, 4096 / 64), blk, 0, stream>>>(
        x, qkv_w, qkv_b, ws_qkv, 4096, 2304, 768, 768, 2304, 2304);

    // 2) z = (scale/H) Qc.Kc^T + gumbel(u)
    zscore_kernel<<<dim3(16, 16, B_), blk, 0, stream>>>(ws_qkv, u, ws_z);

    // 3) exact top-32 threshold per row -> bitmask
    topk_mask_kernel<<<dim3(B_ * N_), dim3(64), 0, stream>>>(ws_z, ws_mask);

    // 4) fused masked flash attention -> out1 (*(mean head_scores))
    flash_masked_kernel<<<dim3(16, H_, B_), blk, 0, stream>>>(
        ws_qkv, ws_mask, head_scores, ws_out1);

    // 5) out = out1 @ proj_w + proj_b
    gemm_nn_bias<<<dim3(768 / 64, 4096 / 64), blk, 0, stream>>>(
        ws_out1, proj_w, proj_b, out, 4096, 768, 768, 768, 768, 768);
}